// Round 1
// baseline (1075.670 us; speedup 1.0000x reference)
//
#include <hip/hip_runtime.h>
#include <hip/hip_bf16.h>
#include <stdint.h>

typedef __attribute__((ext_vector_type(8))) short short8;
typedef __attribute__((ext_vector_type(4))) float floatx4;

#define BQ     2048
#define LMAX   6
#define EMB    256
#define NNODES 63
#define NPOIS  100000
#define HID    128

// fp32 -> bf16 round-to-nearest-even (inputs are finite, no NaN handling needed)
__device__ __forceinline__ unsigned short f2bf(float x) {
  unsigned int u = __float_as_uint(x);
  unsigned int r = (u + 0x7fffu + ((u >> 16) & 1u)) >> 16;
  return (unsigned short)r;
}

// ---------------------------------------------------------------------------
// Kernel 1: convert poi_emb fp32 -> bf16 into workspace; block 0 also detects
// whether path_mask is stored as 1-byte bools or int32 and writes a flag.
// Detection: read the first 12288 bytes as 3072 uint32 words (in-bounds under
// BOTH interpretations). If bytes: some word has a set bit above bit 0
// (every row starts with true, and 6-byte rows misalign with 4-byte words),
// so a word > 1 is guaranteed. If int32: all words are exactly 0 or 1.
// ---------------------------------------------------------------------------
__global__ void convert_detect_kernel(const float* __restrict__ poi,
                                      unsigned short* __restrict__ Bb,
                                      const unsigned int* __restrict__ maskw,
                                      int* __restrict__ flag) {
  if (blockIdx.x == 0) {
    __shared__ int bad;
    if (threadIdx.x == 0) bad = 0;
    __syncthreads();
    int my = 0;
    for (int w = threadIdx.x; w < (BQ * LMAX) / 4; w += 256) {
      if (maskw[w] > 1u) my = 1;
    }
    if (my) atomicOr(&bad, 1);
    __syncthreads();
    if (threadIdx.x == 0) *flag = bad;  // 1 = byte bools, 0 = int32
  }
  size_t idx = (size_t)blockIdx.x * 256 + threadIdx.x;  // 8 floats per thread
  const float4* s4 = (const float4*)poi;
  float4 f0 = s4[idx * 2 + 0];
  float4 f1 = s4[idx * 2 + 1];
  uint4 o;
  o.x = (unsigned)f2bf(f0.x) | ((unsigned)f2bf(f0.y) << 16);
  o.y = (unsigned)f2bf(f0.z) | ((unsigned)f2bf(f0.w) << 16);
  o.z = (unsigned)f2bf(f1.x) | ((unsigned)f2bf(f1.y) << 16);
  o.w = (unsigned)f2bf(f1.z) | ((unsigned)f2bf(f1.w) << 16);
  ((uint4*)Bb)[idx] = o;
}

// ---------------------------------------------------------------------------
// Kernel 2: attention. One block (256 threads) per batch row.
// Computes masked tanh-attention MLP + softmax + weighted sum of path_pref,
// emits pref row as bf16 (A matrix of the scoring GEMM).
// b2 shifts all logits equally -> cancels in softmax -> skipped.
// ---------------------------------------------------------------------------
__global__ void attn_kernel(const int* __restrict__ user,
                            const int* __restrict__ last_poi,
                            const int* __restrict__ path_nodes,
                            const void* __restrict__ path_mask,
                            const float* __restrict__ poi_emb,
                            const float* __restrict__ tree_emb,
                            const float* __restrict__ w1,
                            const float* __restrict__ b1,
                            const float* __restrict__ w2,
                            unsigned short* __restrict__ Abf,
                            const int* __restrict__ flag) {
  __shared__ float pref[LMAX][EMB];
  __shared__ float hmat[LMAX][EMB];
  __shared__ float partial[4][3];
  __shared__ float attnv[LMAX];

  const int b = blockIdx.x;
  const int t = threadIdx.x;
  const int u = user[b];
  const float lpv = poi_emb[((size_t)last_poi[b] << 8) + t];

#pragma unroll
  for (int l = 0; l < LMAX; l++) {
    int node = path_nodes[b * LMAX + l];
    float pv = tree_emb[((size_t)(u * NNODES + node) << 8) + t];
    pref[l][t] = pv;
    hmat[l][t] = tanhf(lpv + pv);
  }
  __syncthreads();

  // MLP: thread j computes hidden unit j for 3 path positions (half 0: l=0..2,
  // half 1: l=3..5); w1 read once per k, shared across the 3 positions.
  const int j = t & 127;
  const int half = t >> 7;
  float y0 = b1[j], y1 = y0, y2 = y0;
  const float* h0 = hmat[half * 3 + 0];
  const float* h1 = hmat[half * 3 + 1];
  const float* h2 = hmat[half * 3 + 2];
  for (int k = 0; k < EMB; k += 4) {
#pragma unroll
    for (int kk = 0; kk < 4; kk++) {
      float w = w1[(k + kk) * HID + j];
      y0 = fmaf(h0[k + kk], w, y0);
      y1 = fmaf(h1[k + kk], w, y1);
      y2 = fmaf(h2[k + kk], w, y2);
    }
  }
  const float w2j = w2[j];
  float s0 = fmaxf(y0, 0.f) * w2j;
  float s1 = fmaxf(y1, 0.f) * w2j;
  float s2 = fmaxf(y2, 0.f) * w2j;
#pragma unroll
  for (int off = 32; off > 0; off >>= 1) {
    s0 += __shfl_down(s0, off);
    s1 += __shfl_down(s1, off);
    s2 += __shfl_down(s2, off);
  }
  const int wid = t >> 6;
  if ((t & 63) == 0) {
    partial[wid][0] = s0; partial[wid][1] = s1; partial[wid][2] = s2;
  }
  __syncthreads();

  if (t < LMAX) {
    int l = t;
    int hh = l / 3, li = l - hh * 3;
    float a = partial[hh * 2][li] + partial[hh * 2 + 1][li];
    bool valid;
    if (*flag)
      valid = ((const unsigned char*)path_mask)[b * LMAX + l] != 0;
    else
      valid = ((const int*)path_mask)[b * LMAX + l] != 0;
    attnv[l] = valid ? a : -1e9f;
  }
  __syncthreads();

  // every thread redundantly computes the 6-way softmax (cheap, avoids sync)
  float mx = attnv[0];
#pragma unroll
  for (int l = 1; l < LMAX; l++) mx = fmaxf(mx, attnv[l]);
  float e[LMAX], sum = 0.f;
#pragma unroll
  for (int l = 0; l < LMAX; l++) { e[l] = expf(attnv[l] - mx); sum += e[l]; }
  float inv = 1.f / sum;
  float outv = 0.f;
#pragma unroll
  for (int l = 0; l < LMAX; l++) outv += e[l] * inv * pref[l][t];
  Abf[((size_t)b << 8) + t] = f2bf(outv);
}

// ---------------------------------------------------------------------------
// Kernel 3: scores = pref @ poi_emb^T  (M=2048, N=100000, K=256, bf16 MFMA).
// m97-style: 128x128 block tile, BK=64, global_load_lds width 16, 2x2 wave
// grid of 64x64 wave tiles, mfma_f32_16x16x32_bf16.
// XOR swizzle (k-chunk ^= row&7) applied on the GLOBAL read side during
// staging (global_load_lds forces lane-contiguous LDS order), undone at
// fragment read -> ds_read_b128 spreads across bank groups (2-way max).
// ---------------------------------------------------------------------------
__global__ void gemm_kernel(const unsigned short* __restrict__ A,
                            const unsigned short* __restrict__ Bb,
                            float* __restrict__ C) {
  __shared__ __align__(16) unsigned short sA[128 * 64];  // 16 KB
  __shared__ __align__(16) unsigned short sB[128 * 64];  // 16 KB

  const int tid = threadIdx.x;
  const int wid = tid >> 6;
  const int lane = tid & 63;
  const int m0 = blockIdx.x * 128;   // M fast dim: 16 M-blocks share a B tile
  const int n0 = blockIdx.y * 128;
  const int wm = wid & 1, wn = wid >> 1;
  const int quad = lane >> 4;
  const int l16 = lane & 15;
  const int kp = tid & 7;

  floatx4 acc[4][4] = {};

  for (int kc = 0; kc < EMB; kc += 64) {
    if (kc) __syncthreads();  // previous chunk fully consumed before overwrite
#pragma unroll
    for (int r = 0; r < 4; r++) {  // stage A chunk: 4 rounds x 256 lanes x 16B
      int q = r * 256 + tid;
      int row = q >> 3;
      int ksz = kp ^ (row & 7);
      const unsigned short* ga = A + ((size_t)(m0 + row) << 8) + kc + ksz * 8;
      __builtin_amdgcn_global_load_lds(
          (const __attribute__((address_space(1))) void*)ga,
          (__attribute__((address_space(3))) void*)((char*)sA + r * 4096 + (wid << 10)),
          16, 0, 0);
    }
#pragma unroll
    for (int r = 0; r < 4; r++) {  // stage B chunk (clamp tail rows, cols >=N never stored)
      int q = r * 256 + tid;
      int row = q >> 3;
      int nrow = n0 + row;
      if (nrow > NPOIS - 1) nrow = NPOIS - 1;
      int ksz = kp ^ (row & 7);
      const unsigned short* gb = Bb + ((size_t)nrow << 8) + kc + ksz * 8;
      __builtin_amdgcn_global_load_lds(
          (const __attribute__((address_space(1))) void*)gb,
          (__attribute__((address_space(3))) void*)((char*)sB + r * 4096 + (wid << 10)),
          16, 0, 0);
    }
    __builtin_amdgcn_s_waitcnt(0);
    __syncthreads();

#pragma unroll
    for (int ks = 0; ks < 2; ks++) {  // two 32-wide k-steps per chunk
      short8 av[4], bv[4];
#pragma unroll
      for (int mt = 0; mt < 4; mt++) {
        int rowA = wm * 64 + mt * 16 + l16;
        int c = (ks * 4 + quad) ^ (rowA & 7);
        av[mt] = *(const short8*)((const char*)sA + rowA * 128 + c * 16);
      }
#pragma unroll
      for (int nt = 0; nt < 4; nt++) {
        int rowB = wn * 64 + nt * 16 + l16;
        int c = (ks * 4 + quad) ^ (rowB & 7);
        bv[nt] = *(const short8*)((const char*)sB + rowB * 128 + c * 16);
      }
#pragma unroll
      for (int mt = 0; mt < 4; mt++)
#pragma unroll
        for (int nt = 0; nt < 4; nt++)
          acc[mt][nt] = __builtin_amdgcn_mfma_f32_16x16x32_bf16(
              av[mt], bv[nt], acc[mt][nt], 0, 0, 0);
    }
  }

  // Epilogue: C/D layout col = lane&15, row = quad*4 + reg
#pragma unroll
  for (int nt = 0; nt < 4; nt++) {
    int n = n0 + wn * 64 + nt * 16 + l16;
    if (n >= NPOIS) continue;
#pragma unroll
    for (int mt = 0; mt < 4; mt++) {
      int mbase = m0 + wm * 64 + mt * 16 + quad * 4;
#pragma unroll
      for (int i = 0; i < 4; i++) {
        C[(size_t)(mbase + i) * NPOIS + n] = acc[mt][nt][i];
      }
    }
  }
}

// ---------------------------------------------------------------------------
extern "C" void kernel_launch(void* const* d_in, const int* in_sizes, int n_in,
                              void* d_out, int out_size, void* d_ws, size_t ws_size,
                              hipStream_t stream) {
  const int*   user       = (const int*)d_in[0];
  const int*   last_poi   = (const int*)d_in[1];
  const int*   path_nodes = (const int*)d_in[2];
  const void*  path_mask  = d_in[3];
  // d_in[4] = num_nodes scalar (always 63, hardcoded)
  const float* poi_emb    = (const float*)d_in[5];
  const float* tree_emb   = (const float*)d_in[6];
  const float* w1         = (const float*)d_in[7];
  const float* b1         = (const float*)d_in[8];
  const float* w2         = (const float*)d_in[9];
  // d_in[10] = b2 (cancels in softmax, unused)
  float* out = (float*)d_out;

  const size_t A_bytes = (size_t)BQ * EMB * 2;        // 1 MiB
  const size_t B_bytes = (size_t)NPOIS * EMB * 2;     // 51.2 MB
  unsigned short* Abf = (unsigned short*)d_ws;
  unsigned short* Bbf = (unsigned short*)((char*)d_ws + A_bytes);
  int* flag = (int*)((char*)d_ws + A_bytes + B_bytes);
  if (ws_size < A_bytes + B_bytes + sizeof(int)) return;  // visible failure if ws too small

  // poi_emb: 25.6M elems / 8 per thread = 3.2M threads = 12500 blocks x 256
  convert_detect_kernel<<<dim3(12500), dim3(256), 0, stream>>>(
      poi_emb, Bbf, (const unsigned int*)path_mask, flag);

  attn_kernel<<<dim3(BQ), dim3(256), 0, stream>>>(
      user, last_poi, path_nodes, path_mask, poi_emb, tree_emb, w1, b1, w2, Abf, flag);

  // N blocks: ceil(100000/128) = 782 ; M blocks: 2048/128 = 16 (fast dim)
  gemm_kernel<<<dim3(16, 782), dim3(256), 0, stream>>>(Abf, Bbf, out);
}